// Round 5
// baseline (22.284 us; speedup 1.0000x reference)
//
#include <hip/hip_runtime.h>

// ResampleLayer: linear time-resampling of [B,S,D] f32 embeddings from sorted
// timestamps ts[B,S] onto a uniform grid of OUT_LEN points in [0, 100].
//
// B=32, S=4096, D=256, OUT_LEN=1001, t_l = l * 0.1.
//
// Structure: one 64-thread wave per (b, 8 consecutive l) -> 4032 waves
// (~16/CU). Lanes run 8 independent per-lane binary searches (p = lane&7),
// then an unrolled 8-point payload: __shfl(_, q) with compile-time q folds to
// v_readlane; each lane lerps one float4 of D=256. Embed reads and out writes
// use non-temporal hints (read-once / write-once; keep L2 for the hot 16 KB
// ts rows). Block ids are XCD-swizzled so adjacent-l blocks (which share ts
// and overlap embed rows) land on the same XCD L2.

#define RS_B 32
#define RS_S 4096
#define RS_D 256
#define RS_OUTLEN 1001
#define RS_PPW 8                                        // points per wave
#define RS_NBX ((RS_OUTLEN + RS_PPW - 1) / RS_PPW)      // 126
#define RS_NWG (RS_NBX * RS_B)                          // 4032 (divisible by 8)

// Native clang vector type: __builtin_nontemporal_* requires a pointer to a
// scalar or vector of scalars (HIP's float4 class does not qualify).
typedef float f32x4 __attribute__((ext_vector_type(4)));

__global__ __launch_bounds__(64) void resample_kernel(
    const float* __restrict__ embed,   // [B, S, D]
    const float* __restrict__ ts,      // [B, S] sorted along S
    float* __restrict__ out)           // [B, OUT_LEN, D]
{
    // XCD-bijective swizzle: consecutive work ids -> same XCD chunk.
    // RS_NWG % 8 == 0, so the simple form is bijective.
    const int lin = blockIdx.x;                    // 0..RS_NWG-1
    const int wg  = (lin & 7) * (RS_NWG / 8) + (lin >> 3);
    const int b   = wg / RS_NBX;
    const int l0  = (wg - b * RS_NBX) * RS_PPW;

    const int lane = threadIdx.x;                  // 0..63
    const int p = lane & (RS_PPW - 1);             // which point this lane searches

    int l = l0 + p;
    if (l > RS_OUTLEN - 1) l = RS_OUTLEN - 1;      // clamp; tail results unused
    // t matches jnp.linspace(0, 100, 1001)[l] == l * 0.1 (double-derived).
    const float t = (float)((double)l * (100.0 / 1000.0));

    const float* __restrict__ tsr = ts + (size_t)b * RS_S;

    // Per-lane lower_bound: first i in [0, S] with tsr[i] >= t. 12 fixed
    // steps (S = 2^12); ts row is 16 KB -> L1/L2-resident.
    int lo = 0, hi = RS_S;
#pragma unroll
    for (int it = 0; it < 12; ++it) {
        int mid = (lo + hi) >> 1;
        float v = tsr[mid];
        if (v < t) lo = mid + 1; else hi = mid;
    }
    int idx = lo;
    if (idx < 1) idx = 1;
    if (idx > RS_S - 1) idx = RS_S - 1;

    const float x_lo = tsr[idx - 1];
    const float x_hi = tsr[idx];
    const float w1 = (t - x_lo) / (x_hi - x_lo);   // r = a + (c-a)*w1

    const f32x4* __restrict__ ebase =
        (const f32x4*)(embed + (size_t)b * RS_S * RS_D);   // row stride 64 f32x4
    f32x4* __restrict__ obase =
        (f32x4*)(out + ((size_t)b * RS_OUTLEN + (size_t)l0) * RS_D);

#pragma unroll
    for (int q = 0; q < RS_PPW; ++q) {
        if (l0 + q > RS_OUTLEN - 1) break;         // uniform tail exit
        const int   sidx = __shfl(idx, q);         // compile-time q -> v_readlane
        const float sw   = __shfl(w1,  q);

        const f32x4* plo = ebase + (size_t)(sidx - 1) * (RS_D / 4) + lane;
        const f32x4* phi = plo + (RS_D / 4);
        f32x4 a = __builtin_nontemporal_load(plo);
        f32x4 c = __builtin_nontemporal_load(phi);
        f32x4 r = a + (c - a) * sw;
        __builtin_nontemporal_store(r, obase + (size_t)q * (RS_D / 4) + lane);
    }
}

extern "C" void kernel_launch(void* const* d_in, const int* in_sizes, int n_in,
                              void* d_out, int out_size, void* d_ws, size_t ws_size,
                              hipStream_t stream) {
    const float* embed = (const float*)d_in[0];  // [32, 4096, 256] f32
    const float* ts    = (const float*)d_in[1];  // [32, 4096] f32 sorted
    float* out         = (float*)d_out;          // [32, 1001, 256] f32

    resample_kernel<<<RS_NWG, 64, 0, stream>>>(embed, ts, out);
}

// Round 6
// 21.094 us; speedup vs baseline: 1.0564x; 1.0564x over previous
//
#include <hip/hip_runtime.h>

// ResampleLayer: linear time-resampling of [B,S,D] f32 embeddings from sorted
// timestamps ts[B,S] onto a uniform grid of OUT_LEN points in [0, 100].
//
// B=32, S=4096, D=256, OUT_LEN=1001, t_l = l * 0.1.
//
// Structure: 256-thread blocks (4 waves); each wave owns a strip of 8
// consecutive output points. Search is a 2-round wave-parallel ballot scheme
// (no dependent binary-search chain): round 1, lane i samples the last
// element of 64-element chunk i -> ballot per point gives its chunk; round 2,
// window load of that chunk -> ballot gives the exact lower_bound. Results
// are wave-uniform. Payload: all 16 row loads issued into registers in one
// unrolled, branch-free loop (16 global_load_dwordx4 in flight per wave),
// then lerp+store. Tail strip overlaps (starts at 993) so every strip is
// full — duplicate writes carry identical values (deterministic).

#define RS_B 32
#define RS_S 4096
#define RS_D 256
#define RS_OUTLEN 1001
#define RS_PPW 8                         // points per wave (strip)
#define RS_NSTRIP 126                    // ceil(1001/8); last starts at 993
#define RS_WPB 4                         // waves per block
#define RS_NBX 32                        // ceil(126/4)

typedef float f32x4 __attribute__((ext_vector_type(4)));

__global__ __launch_bounds__(256, 4) void resample_kernel(
    const float* __restrict__ embed,   // [B, S, D]
    const float* __restrict__ ts,      // [B, S] sorted along S
    float* __restrict__ out)           // [B, OUT_LEN, D]
{
    // XCD-contiguous swizzle over the 1024-block grid (1024 % 8 == 0).
    const int lin = blockIdx.x;                    // 0..1023
    const int wg  = (lin & 7) * (RS_NBX * RS_B / 8) + (lin >> 3);
    const int b   = wg >> 5;                       // 0..31
    const int bx  = wg & 31;                       // 0..31

    const int wave = threadIdx.x >> 6;
    const int lane = threadIdx.x & 63;

    int sid = bx * RS_WPB + wave;                  // 0..127
    if (sid > RS_NSTRIP - 1) sid = RS_NSTRIP - 1;  // dup strips: identical writes
    int l0 = sid * RS_PPW;
    if (l0 > RS_OUTLEN - RS_PPW) l0 = RS_OUTLEN - RS_PPW;   // 993 (overlap)

    const float* __restrict__ tsr = ts + (size_t)b * RS_S;

    // ---- 2-round ballot search for all 8 points (results wave-uniform) ----
    // Round 1: lane i holds the LAST element of chunk i (64 chunks x 64).
    const float s1 = tsr[lane * 64 + 63];
    int cq[RS_PPW];
#pragma unroll
    for (int q = 0; q < RS_PPW; ++q) {
        const float tq = (float)((double)(l0 + q) * 0.1);
        cq[q] = __popcll(__ballot(s1 < tq));       // 0..64; ==64 -> idx = S
    }
    // Round 2: scan each point's chunk; lower_bound = c*64 + popcount.
    int idxq[RS_PPW];
#pragma unroll
    for (int q = 0; q < RS_PPW; ++q) {
        const float tq = (float)((double)(l0 + q) * 0.1);
        const int c = cq[q] < 63 ? cq[q] : 63;     // dummy chunk when cq==64
        const float w = tsr[c * 64 + lane];
        const int cnt = __popcll(__ballot(w < tq));
        int idx = (cq[q] >= 64) ? RS_S : c * 64 + cnt;
        if (idx < 1) idx = 1;
        if (idx > RS_S - 1) idx = RS_S - 1;
        idxq[q] = idx;
    }
    // Interpolation weights (same-address loads broadcast; ts row L1-hot).
    float swq[RS_PPW];
#pragma unroll
    for (int q = 0; q < RS_PPW; ++q) {
        const float tq = (float)((double)(l0 + q) * 0.1);
        const float x_lo = tsr[idxq[q] - 1];
        const float x_hi = tsr[idxq[q]];
        swq[q] = (tq - x_lo) / (x_hi - x_lo);
    }

    // ---- payload: 16 independent row loads, then lerp + store ----
    const f32x4* __restrict__ ebase =
        (const f32x4*)(embed + (size_t)b * RS_S * RS_D);    // row = 64 f32x4
    f32x4* __restrict__ obase =
        (f32x4*)(out + ((size_t)b * RS_OUTLEN + (size_t)l0) * RS_D);

    f32x4 va[RS_PPW], vc[RS_PPW];
#pragma unroll
    for (int q = 0; q < RS_PPW; ++q) {
        const f32x4* plo = ebase + (size_t)(idxq[q] - 1) * (RS_D / 4) + lane;
        va[q] = __builtin_nontemporal_load(plo);
        vc[q] = __builtin_nontemporal_load(plo + (RS_D / 4));
    }
#pragma unroll
    for (int q = 0; q < RS_PPW; ++q) {
        f32x4 r = va[q] + (vc[q] - va[q]) * swq[q];
        __builtin_nontemporal_store(r, obase + (size_t)q * (RS_D / 4) + lane);
    }
}

extern "C" void kernel_launch(void* const* d_in, const int* in_sizes, int n_in,
                              void* d_out, int out_size, void* d_ws, size_t ws_size,
                              hipStream_t stream) {
    const float* embed = (const float*)d_in[0];  // [32, 4096, 256] f32
    const float* ts    = (const float*)d_in[1];  // [32, 4096] f32 sorted
    float* out         = (float*)d_out;          // [32, 1001, 256] f32

    resample_kernel<<<RS_NBX * RS_B, RS_WPB * 64, 0, stream>>>(embed, ts, out);
}